// Round 2
// baseline (434.622 us; speedup 1.0000x reference)
//
#include <hip/hip_runtime.h>
#include <hip/hip_bf16.h>

typedef __attribute__((ext_vector_type(8))) short short8;
typedef __attribute__((ext_vector_type(4))) float floatx4;
typedef __attribute__((ext_vector_type(16))) float floatx16;

#define N_ROWS 32768
#define D_DIM  128
#define H_KEYS 8192
#define C_COLS 100
#define LOG2E  1.4426950408889634f

// workspace layout (total 3,964,928 B — identical to the known-good footprint)
#define KP_BYTES  (H_KEYS * D_DIM * 2)        // 2,097,152: K packed, 32x32x16 A-frag order
#define VP_BYTES  (512 * 3584)                // 1,835,008: V packed 112-col units
#define KSQ_OFF   (KP_BYTES + VP_BYTES)       // 3,932,160: ksq in D-reg order, 32 KB

// v_cvt_pk_bf16_f32: two fp32 -> packed bf16 (a low, b high)
__device__ __forceinline__ unsigned int pk2bf(float a, float b) {
  union { __hip_bfloat162 h; unsigned int u; } c;
  c.h = __float22bfloat162_rn(float2{a, b});
  return c.u;
}

// async global->LDS; LDS dest = wave-uniform base + lane*width
__device__ __forceinline__ void glds16(const void* g, void* l) {
  __builtin_amdgcn_global_load_lds(
      (const __attribute__((address_space(1))) unsigned int*)g,
      (__attribute__((address_space(3))) unsigned int*)l, 16, 0, 0);
}
__device__ __forceinline__ void glds4(const void* g, void* l) {
  __builtin_amdgcn_global_load_lds(
      (const __attribute__((address_space(1))) unsigned int*)g,
      (__attribute__((address_space(3))) unsigned int*)l, 4, 0, 0);
}

// ---------------------------------------------------------------------------
// pack_k32: K [8192x128] fp32 -> 32x32x16 MFMA A-fragment order, scaled by
// 2*log2e/T; also emits ksqp[kt][hh][reg] = -|k|^2*log2e/T in the exact
// C/D-register order of the 32x32 tile (key = (reg&3)+8*(reg>>2)+4*hh).
// One block per 32-key tile.
// ---------------------------------------------------------------------------
__global__ __launch_bounds__(256) void pack_k32(const float* __restrict__ keys,
                                                const float* __restrict__ temp,
                                                unsigned short* __restrict__ kp,
                                                float* __restrict__ ksqp) {
  __shared__ __align__(16) float kt_lds[32 * 132];
  __shared__ float aux[32 * 8];
  __shared__ float ssq[32];
  const int kt = blockIdx.x;
  const int t = threadIdx.x;
  const float* src = keys + (size_t)kt * 4096;
#pragma unroll
  for (int i = 0; i < 4; ++i) {
    int idx = i * 1024 + t * 4;
    float4 v = *(const float4*)(src + idx);
    int row = idx >> 7, col = idx & 127;
    *(float4*)(&kt_lds[row * 132 + col]) = v;
  }
  __syncthreads();
  {
    int row = t >> 3, seg = t & 7;
    const float* p = &kt_lds[row * 132 + seg * 16];
    float s = 0.f;
#pragma unroll
    for (int j = 0; j < 16; ++j) s += p[j] * p[j];
    aux[row * 8 + seg] = s;
  }
  __syncthreads();
  const float tv = temp[0];
  if (t < 32) {
    float s = 0.f;
#pragma unroll
    for (int j = 0; j < 8; ++j) s += aux[t * 8 + j];
    ssq[t] = s;
  }
  __syncthreads();
  if (t < 32) {
    int h = t >> 4, reg = t & 15;
    int key = (reg & 3) + 8 * (reg >> 2) + 4 * h;
    ksqp[((size_t)kt * 2 + h) * 16 + reg] = -ssq[key] * LOG2E / tv;
  }
  const float kscale = 2.0f * LOG2E / tv;
#pragma unroll
  for (int u0 = 0; u0 < 2; ++u0) {
    int u = t + u0 * 256;            // 512 tasks: 8 dc x 64 lanes
    int dc = u >> 6, l = u & 63;
    const float* p = &kt_lds[(l & 31) * 132 + dc * 16 + (l >> 5) * 8];
    union { short8 v; unsigned int ui[4]; } cv;
#pragma unroll
    for (int j = 0; j < 4; ++j)
      cv.ui[j] = pk2bf(p[2 * j] * kscale, p[2 * j + 1] * kscale);
    *(short8*)(kp + ((size_t)(kt * 8 + dc) * 64 + l) * 8) = cv.v;
  }
}

// ---------------------------------------------------------------------------
// pack_v32: V [8192x100] -> 32x32x16 B-frag units of 3584 B per (32-key b,
// 16-key kc): nt 0..2 full 32-col tiles (1024 B each) + nt 3 half-tile
// (cols 96..111 only, 512 B; col 100 = 1.0 -> denominator, 101..111 = 0).
// Cols 112..127 are zeroed at PV time via cndmask.
// ---------------------------------------------------------------------------
__global__ __launch_bounds__(256) void pack_v32(const float* __restrict__ values,
                                                unsigned short* __restrict__ vp) {
  __shared__ float vt[32 * 104];
  const int b = blockIdx.x;        // keys [32b, 32b+32)
  const int t = threadIdx.x;
  const float* src = values + (size_t)b * 32 * C_COLS;
  for (int idx = t; idx < 32 * C_COLS; idx += 256) {
    int row = idx / C_COLS, col = idx - row * C_COLS;
    vt[row * 104 + col] = src[idx];
  }
  __syncthreads();
  unsigned short* dst = vp + (size_t)b * 2 * 1792;   // 2 units of 1792 ushorts
#pragma unroll
  for (int u0 = 0; u0 < 2; ++u0) {
    int u = t + u0 * 256;            // 448 tasks: 384 full-tile + 64 half-tile
    if (u < 384) {
      int kc = u / 192, rem = u - kc * 192;
      int nt = rem >> 6, l = rem & 63;
      int col = nt * 32 + (l & 31);
      int k0 = kc * 16 + (l >> 5) * 8;
      union { short8 v; unsigned int ui[4]; } cv;
#pragma unroll
      for (int j = 0; j < 4; ++j)
        cv.ui[j] = pk2bf(vt[(k0 + 2 * j) * 104 + col], vt[(k0 + 2 * j + 1) * 104 + col]);
      *(short8*)(dst + kc * 1792 + nt * 512 + l * 8) = cv.v;
    } else if (u < 448) {
      int v = u - 384;               // 0..63
      int kc = v >> 5, slot = v & 31;
      int hh = slot >> 4, c16 = slot & 15;
      int col = 96 + c16;
      int k0 = kc * 16 + hh * 8;
      union { short8 v8; unsigned int ui[4]; } cv;
#pragma unroll
      for (int j = 0; j < 4; ++j) {
        float a  = (col < C_COLS) ? vt[(k0 + 2 * j) * 104 + col]
                                  : (col == C_COLS ? 1.0f : 0.0f);
        float bb = (col < C_COLS) ? vt[(k0 + 2 * j + 1) * 104 + col]
                                  : (col == C_COLS ? 1.0f : 0.0f);
        cv.ui[j] = pk2bf(a, bb);
      }
      *(short8*)(dst + kc * 1792 + 1536 + slot * 8) = cv.v8;
    }
  }
}

// ---------------------------------------------------------------------------
// attn_rbf32: register-resident P via 32x32x16 tiles + v_permlane32_swap_b32.
// Block = 512 threads (8 waves) = 128 x-rows x 2 key-halves:
//   wave w: key-half h = w>>2 (4096 keys), x-row slice s = w&3 (32 rows).
// S^T = K.X^T (C init = -|k|^2*log2e/T): D-layout col(lane&31) = x-row ==
// PV A-operand row(lane&31); key-axis fixup = one permlane32_swap per dword
// pair. V double-buffered in LDS via global_load_lds (lane-linear ->
// conflict-free ds_read_b128). One balanced barrier/iter. Halves combined in
// LDS at the end; col 100 = denominator.
// ---------------------------------------------------------------------------
__global__ __launch_bounds__(512, 2)
void attn_rbf32(const float* __restrict__ x,
                const unsigned short* __restrict__ kp,
                const unsigned short* __restrict__ vp,
                const float* __restrict__ ksqp,
                float* __restrict__ out) {
  __shared__ __align__(16) char smem[57344];   // 4 x 14336B V tiles [half][parity]
  const int tid = threadIdx.x;
  const int w = tid >> 6;
  const int lane = tid & 63;
  const int l31 = lane & 31;
  const int hh = lane >> 5;            // lane half (key sub-group)
  const int h = w >> 2;                // key half 0/1
  const int s = w & 3;                 // x-row slice
  const int rb = blockIdx.x;           // rows [128rb, 128rb+128)

  // X B-fragments for this wave's 32 rows: xf[dc][j] = X[row][dc*16+hh*8+j]
  short8 xf[8];
  {
    const float* xr = x + ((size_t)rb * 128 + s * 32 + l31) * D_DIM + hh * 8;
#pragma unroll
    for (int dc = 0; dc < 8; ++dc) {
      float4 lo = *(const float4*)(xr + dc * 16);
      float4 hi = *(const float4*)(xr + dc * 16 + 4);
      union { short8 v; unsigned int ui[4]; } cv;
      cv.ui[0] = pk2bf(lo.x, lo.y); cv.ui[1] = pk2bf(lo.z, lo.w);
      cv.ui[2] = pk2bf(hi.x, hi.y); cv.ui[3] = pk2bf(hi.z, hi.w);
      xf[dc] = cv.v;
    }
  }

  floatx16 oacc[4];
#pragma unroll
  for (int nt = 0; nt < 4; ++nt) oacc[nt] = (floatx16)0.0f;

  const int kt0 = h * 128;             // first 32-key tile of this half
  const char* vpg = (const char*)vp;

  // staging helper offsets: wave s stages unit s of the 4-unit (14336B) tile
  // unit U = (h*128 + it*2 + (s>>1))*2 + (s&1), 3584 B each
  // prologue: stage V(it=0) into parity 0
  {
    const char* g = vpg + (size_t)((h * 128 + (s >> 1)) * 2 + (s & 1)) * 3584;
    char* ldst = smem + (h * 2 + 0) * 14336 + s * 3584;
    glds16(g + lane * 16, ldst);
    glds16(g + 1024 + lane * 16, ldst + 1024);
    glds16(g + 2048 + lane * 16, ldst + 2048);
    glds4(g + 3072 + lane * 4, ldst + 3072);
    glds4(g + 3328 + lane * 4, ldst + 3328);
  }
  __syncthreads();

#pragma unroll 2
  for (int it = 0; it < 64; ++it) {
    const char* cur = smem + (h * 2 + (it & 1)) * 14336;
    // prefetch V(it+1) -> other parity (its readers finished at it-1 barrier)
    if (it < 63) {
      const char* g = vpg +
          (size_t)((h * 128 + (it + 1) * 2 + (s >> 1)) * 2 + (s & 1)) * 3584;
      char* ldst = smem + (h * 2 + ((it + 1) & 1)) * 14336 + s * 3584;
      glds16(g + lane * 16, ldst);
      glds16(g + 1024 + lane * 16, ldst + 1024);
      glds16(g + 2048 + lane * 16, ldst + 2048);
      glds4(g + 3072 + lane * 4, ldst + 3072);
      glds4(g + 3328 + lane * 4, ldst + 3328);
    }

    // ---- QK^T + exp2 + in-register transpose, one 32-key tile at a time ----
    short8 paf[4];                      // PV A-frags, one per 16-key chunk
#pragma unroll
    for (int tt = 0; tt < 2; ++tt) {
      const int kt = kt0 + it * 2 + tt;
      floatx16 acc;
      {
        const floatx4* kq = (const floatx4*)(ksqp + ((size_t)kt * 2 + hh) * 16);
#pragma unroll
        for (int j = 0; j < 4; ++j) {
          floatx4 v = kq[j];
          acc[4 * j + 0] = v[0]; acc[4 * j + 1] = v[1];
          acc[4 * j + 2] = v[2]; acc[4 * j + 3] = v[3];
        }
      }
#pragma unroll
      for (int dc = 0; dc < 8; ++dc) {
        short8 kf = *(const short8*)(kp + ((size_t)(kt * 8 + dc) * 64 + lane) * 8);
        acc = __builtin_amdgcn_mfma_f32_32x32x16_bf16(kf, xf[dc], acc, 0, 0, 0);
      }
      // p[j] = pk(exp2) of reg pair (2j,2j+1); swap(p0,p2) yields A-dword0
      // (keys 8hh+0,1) and A-dword2 (keys 8hh+4,5) simultaneously; etc.
      unsigned int p[8];
#pragma unroll
      for (int j = 0; j < 8; ++j)
        p[j] = pk2bf(__builtin_amdgcn_exp2f(acc[2 * j]),
                     __builtin_amdgcn_exp2f(acc[2 * j + 1]));
      asm("v_permlane32_swap_b32 %0, %1" : "+v"(p[0]), "+v"(p[2]));
      asm("v_permlane32_swap_b32 %0, %1" : "+v"(p[1]), "+v"(p[3]));
      asm("v_permlane32_swap_b32 %0, %1" : "+v"(p[4]), "+v"(p[6]));
      asm("v_permlane32_swap_b32 %0, %1" : "+v"(p[5]), "+v"(p[7]));
      union { short8 v; unsigned int ui[4]; } c0, c1;
      c0.ui[0] = p[0]; c0.ui[1] = p[1]; c0.ui[2] = p[2]; c0.ui[3] = p[3];
      c1.ui[0] = p[4]; c1.ui[1] = p[5]; c1.ui[2] = p[6]; c1.ui[3] = p[7];
      paf[tt * 2 + 0] = c0.v;
      paf[tt * 2 + 1] = c1.v;
    }

    // ---- PV: O += P.V  (4 indep oacc chains; lane-linear b128 reads) ----
#pragma unroll
    for (int kc = 0; kc < 4; ++kc) {
      const char* unit = cur + kc * 3584;
#pragma unroll
      for (int nt = 0; nt < 3; ++nt) {
        short8 vf = *(const short8*)(unit + nt * 1024 + lane * 16);
        oacc[nt] = __builtin_amdgcn_mfma_f32_32x32x16_bf16(paf[kc], vf, oacc[nt], 0, 0, 0);
      }
      // nt=3 half-tile: cols 96..111 stored; 112..127 are zero
      short8 vf = *(const short8*)(unit + 3072 + (hh * 16 + (l31 & 15)) * 16);
      if (l31 >= 16) vf = (short8)0;
      oacc[3] = __builtin_amdgcn_mfma_f32_32x32x16_bf16(paf[kc], vf, oacc[3], 0, 0, 0);
    }
    __syncthreads();   // V(it) reads done + V(it+1) landed (vmcnt drained)
  }

  // ---- epilogue: combine key-halves in LDS, divide by denominator ----
  float* OL = (float*)smem;            // [128][105] fp32, overlays V bufs
  const int OLS = 105;
  float* rden = (float*)(smem + 128 * OLS * 4);   // +53760, 128 floats
  if (h == 0) {
#pragma unroll
    for (int nt = 0; nt < 4; ++nt) {
      int col = nt * 32 + l31;
      if (col <= C_COLS) {
#pragma unroll
        for (int r = 0; r < 16; ++r) {
          int row = s * 32 + (r & 3) + 8 * (r >> 2) + 4 * hh;
          OL[row * OLS + col] = oacc[nt][r];
        }
      }
    }
  }
  __syncthreads();
  if (h == 1) {
#pragma unroll
    for (int nt = 0; nt < 4; ++nt) {
      int col = nt * 32 + l31;
      if (col <= C_COLS) {
#pragma unroll
        for (int r = 0; r < 16; ++r) {
          int row = s * 32 + (r & 3) + 8 * (r >> 2) + 4 * hh;
          OL[row * OLS + col] += oacc[nt][r];
        }
      }
    }
  }
  __syncthreads();
  if (tid < 128) rden[tid] = 1.0f / OL[tid * OLS + C_COLS];
  __syncthreads();
  float* outb = out + (size_t)rb * (128 * C_COLS);
  for (int idx = tid; idx < 128 * C_COLS; idx += 512) {
    int r = idx / C_COLS;
    int c = idx - r * C_COLS;
    outb[idx] = OL[r * OLS + c] * rden[r];
  }
}

extern "C" void kernel_launch(void* const* d_in, const int* in_sizes, int n_in,
                              void* d_out, int out_size, void* d_ws, size_t ws_size,
                              hipStream_t stream) {
  (void)in_sizes; (void)n_in; (void)out_size; (void)ws_size;
  const float* x      = (const float*)d_in[0];
  const float* keys   = (const float*)d_in[1];
  const float* values = (const float*)d_in[2];
  const float* temp   = (const float*)d_in[3];
  float* out = (float*)d_out;

  char* ws = (char*)d_ws;
  unsigned short* kp   = (unsigned short*)(ws);
  unsigned short* vp   = (unsigned short*)(ws + KP_BYTES);
  float*          ksqp = (float*)(ws + KSQ_OFF);

  hipLaunchKernelGGL(pack_k32,   dim3(256), dim3(256), 0, stream, keys, temp, kp, ksqp);
  hipLaunchKernelGGL(pack_v32,   dim3(256), dim3(256), 0, stream, values, vp);
  hipLaunchKernelGGL(attn_rbf32, dim3(256), dim3(512), 0, stream, x, kp, vp, ksqp, out);
}

// Round 3
// 235.149 us; speedup vs baseline: 1.8483x; 1.8483x over previous
//
#include <hip/hip_runtime.h>
#include <hip/hip_bf16.h>

typedef __attribute__((ext_vector_type(8))) short short8;
typedef __attribute__((ext_vector_type(4))) float floatx4;
typedef __attribute__((ext_vector_type(16))) float floatx16;

#define N_ROWS 32768
#define D_DIM  128
#define H_KEYS 8192
#define C_COLS 100
#define LOG2E  1.4426950408889634f

// workspace layout (total 3,964,928 B — proven footprint)
#define KP_BYTES  (H_KEYS * D_DIM * 2)        // 2,097,152: K packed, 32x32x16 A-frag order
#define VP_BYTES  (512 * 3584)                // 1,835,008: V packed 112-col units
#define KSQ_OFF   (KP_BYTES + VP_BYTES)       // 3,932,160: ksq in D-reg order, 32 KB

// v_cvt_pk_bf16_f32: two fp32 -> packed bf16 (a low, b high)
__device__ __forceinline__ unsigned int pk2bf(float a, float b) {
  union { __hip_bfloat162 h; unsigned int u; } c;
  c.h = __float22bfloat162_rn(float2{a, b});
  return c.u;
}

// async global->LDS; global addr per-lane, LDS dest = wave-uniform base + lane*width
__device__ __forceinline__ void glds16(const void* g, void* l) {
  __builtin_amdgcn_global_load_lds(
      (const __attribute__((address_space(1))) unsigned int*)g,
      (__attribute__((address_space(3))) unsigned int*)l, 16, 0, 0);
}
__device__ __forceinline__ void glds4(const void* g, void* l) {
  __builtin_amdgcn_global_load_lds(
      (const __attribute__((address_space(1))) unsigned int*)g,
      (__attribute__((address_space(3))) unsigned int*)l, 4, 0, 0);
}

// ---------------------------------------------------------------------------
// pack_k32: K [8192x128] fp32 -> 32x32x16 MFMA A-fragment order, scaled by
// 2*log2e/T; also emits ksqp[kt][hh][reg] = -|k|^2*log2e/T in the exact
// C/D-register order of the 32x32 tile (key = (reg&3)+8*(reg>>2)+4*hh).
// (unchanged — harness-verified)
// ---------------------------------------------------------------------------
__global__ __launch_bounds__(256) void pack_k32(const float* __restrict__ keys,
                                                const float* __restrict__ temp,
                                                unsigned short* __restrict__ kp,
                                                float* __restrict__ ksqp) {
  __shared__ __align__(16) float kt_lds[32 * 132];
  __shared__ float aux[32 * 8];
  __shared__ float ssq[32];
  const int kt = blockIdx.x;
  const int t = threadIdx.x;
  const float* src = keys + (size_t)kt * 4096;
#pragma unroll
  for (int i = 0; i < 4; ++i) {
    int idx = i * 1024 + t * 4;
    float4 v = *(const float4*)(src + idx);
    int row = idx >> 7, col = idx & 127;
    *(float4*)(&kt_lds[row * 132 + col]) = v;
  }
  __syncthreads();
  {
    int row = t >> 3, seg = t & 7;
    const float* p = &kt_lds[row * 132 + seg * 16];
    float s = 0.f;
#pragma unroll
    for (int j = 0; j < 16; ++j) s += p[j] * p[j];
    aux[row * 8 + seg] = s;
  }
  __syncthreads();
  const float tv = temp[0];
  if (t < 32) {
    float s = 0.f;
#pragma unroll
    for (int j = 0; j < 8; ++j) s += aux[t * 8 + j];
    ssq[t] = s;
  }
  __syncthreads();
  if (t < 32) {
    int h = t >> 4, reg = t & 15;
    int key = (reg & 3) + 8 * (reg >> 2) + 4 * h;
    ksqp[((size_t)kt * 2 + h) * 16 + reg] = -ssq[key] * LOG2E / tv;
  }
  const float kscale = 2.0f * LOG2E / tv;
#pragma unroll
  for (int u0 = 0; u0 < 2; ++u0) {
    int u = t + u0 * 256;            // 512 tasks: 8 dc x 64 lanes
    int dc = u >> 6, l = u & 63;
    const float* p = &kt_lds[(l & 31) * 132 + dc * 16 + (l >> 5) * 8];
    union { short8 v; unsigned int ui[4]; } cv;
#pragma unroll
    for (int j = 0; j < 4; ++j)
      cv.ui[j] = pk2bf(p[2 * j] * kscale, p[2 * j + 1] * kscale);
    *(short8*)(kp + ((size_t)(kt * 8 + dc) * 64 + l) * 8) = cv.v;
  }
}

// ---------------------------------------------------------------------------
// pack_v32: V [8192x100] -> 32x32x16 B-frag units of 3584 B per (32-key b,
// 16-key kc): nt 0..2 full 32-col tiles + nt 3 half-tile (cols 96..111;
// col 100 = 1.0 -> denominator). (unchanged — harness-verified)
// ---------------------------------------------------------------------------
__global__ __launch_bounds__(256) void pack_v32(const float* __restrict__ values,
                                                unsigned short* __restrict__ vp) {
  __shared__ float vt[32 * 104];
  const int b = blockIdx.x;        // keys [32b, 32b+32)
  const int t = threadIdx.x;
  const float* src = values + (size_t)b * 32 * C_COLS;
  for (int idx = t; idx < 32 * C_COLS; idx += 256) {
    int row = idx / C_COLS, col = idx - row * C_COLS;
    vt[row * 104 + col] = src[idx];
  }
  __syncthreads();
  unsigned short* dst = vp + (size_t)b * 2 * 1792;   // 2 units of 1792 ushorts
#pragma unroll
  for (int u0 = 0; u0 < 2; ++u0) {
    int u = t + u0 * 256;            // 448 tasks: 384 full-tile + 64 half-tile
    if (u < 384) {
      int kc = u / 192, rem = u - kc * 192;
      int nt = rem >> 6, l = rem & 63;
      int col = nt * 32 + (l & 31);
      int k0 = kc * 16 + (l >> 5) * 8;
      union { short8 v; unsigned int ui[4]; } cv;
#pragma unroll
      for (int j = 0; j < 4; ++j)
        cv.ui[j] = pk2bf(vt[(k0 + 2 * j) * 104 + col], vt[(k0 + 2 * j + 1) * 104 + col]);
      *(short8*)(dst + kc * 1792 + nt * 512 + l * 8) = cv.v;
    } else if (u < 448) {
      int v = u - 384;               // 0..63
      int kc = v >> 5, slot = v & 31;
      int hh = slot >> 4, c16 = slot & 15;
      int col = 96 + c16;
      int k0 = kc * 16 + hh * 8;
      union { short8 v8; unsigned int ui[4]; } cv;
#pragma unroll
      for (int j = 0; j < 4; ++j) {
        float a  = (col < C_COLS) ? vt[(k0 + 2 * j) * 104 + col]
                                  : (col == C_COLS ? 1.0f : 0.0f);
        float bb = (col < C_COLS) ? vt[(k0 + 2 * j + 1) * 104 + col]
                                  : (col == C_COLS ? 1.0f : 0.0f);
        cv.ui[j] = pk2bf(a, bb);
      }
      *(short8*)(dst + kc * 1792 + 1536 + slot * 8) = cv.v8;
    }
  }
}

// ---------------------------------------------------------------------------
// attn_rbf32: register-resident P via 32x32x16 tiles + v_permlane32_swap_b32.
// Block = 256 threads (4 waves) = 64 x-rows, ALL MFMA operands from LDS:
//   wave (s,t): s = row slice (32 rows), t = key tile within the iter pair.
// Per iter: 64 keys (2 tiles). K (16 KB) and V (14 KB) staged by
// global_load_lds, double-buffered; kf/vf via lane-linear ds_read_b128
// (conflict-free). S^T = K.X^T with C init = -|k|^2*log2e/T; key-axis fixup
// via permlane32_swap; O += P.V accumulated per-t, combined in LDS epilogue.
// Grid 512 -> 2 blocks/CU so barriers of one block hide under the other.
// ---------------------------------------------------------------------------
__global__ __launch_bounds__(256, 2)
void attn_rbf32(const float* __restrict__ x,
                const unsigned short* __restrict__ kp,
                const unsigned short* __restrict__ vp,
                const float* __restrict__ ksqp,
                float* __restrict__ out) {
  __shared__ __align__(16) char smem[61440];  // K: 2x16384 @0 | V: 2x14336 @32768
  const int tid = threadIdx.x;
  const int w = tid >> 6;
  const int lane = tid & 63;
  const int l31 = lane & 31;
  const int hh = lane >> 5;            // lane half (key sub-group)
  const int s = w >> 1;                // x-row slice 0/1
  const int t = w & 1;                 // key tile within pair
  const int rb = blockIdx.x;           // rows [64rb, 64rb+64)

  // X B-fragments for this wave's 32 rows: xf[dc][j] = X[row][dc*16+hh*8+j]
  short8 xf[8];
  {
    const float* xr = x + ((size_t)rb * 64 + s * 32 + l31) * D_DIM + hh * 8;
#pragma unroll
    for (int dc = 0; dc < 8; ++dc) {
      float4 lo = *(const float4*)(xr + dc * 16);
      float4 hi = *(const float4*)(xr + dc * 16 + 4);
      union { short8 v; unsigned int ui[4]; } cv;
      cv.ui[0] = pk2bf(lo.x, lo.y); cv.ui[1] = pk2bf(lo.z, lo.w);
      cv.ui[2] = pk2bf(hi.x, hi.y); cv.ui[3] = pk2bf(hi.z, hi.w);
      xf[dc] = cv.v;
    }
  }

  floatx16 oacc[4];
#pragma unroll
  for (int nt = 0; nt < 4; ++nt) oacc[nt] = (floatx16)0.0f;

  const char* kpg = (const char*)kp;
  const char* vpg = (const char*)vp;

  // prologue: stage iter 0 into parity 0 (wave w stages its quarter)
  {
    const char* gk = kpg + (size_t)w * 4096;
    char* lk = smem + w * 4096;
#pragma unroll
    for (int i = 0; i < 4; ++i) glds16(gk + i * 1024 + lane * 16, lk + i * 1024);
    const char* gv = vpg + (size_t)w * 3584;
    char* lv = smem + 32768 + w * 3584;
    glds16(gv + lane * 16, lv);
    glds16(gv + 1024 + lane * 16, lv + 1024);
    glds16(gv + 2048 + lane * 16, lv + 2048);
    glds4(gv + 3072 + lane * 4, lv + 3072);
    glds4(gv + 3328 + lane * 4, lv + 3328);
  }
  __syncthreads();

#pragma unroll 2
  for (int it = 0; it < 128; ++it) {
    const int p = it & 1;
    const char* Kb = smem + p * 16384;
    const char* Vb = smem + 32768 + p * 14336;

    // prefetch iter it+1 into the other parity (readers done at it-1 barrier)
    if (it < 127) {
      const char* gk = kpg + (size_t)(it + 1) * 16384 + w * 4096;
      char* lk = smem + (p ^ 1) * 16384 + w * 4096;
#pragma unroll
      for (int i = 0; i < 4; ++i) glds16(gk + i * 1024 + lane * 16, lk + i * 1024);
      const char* gv = vpg + (size_t)(it + 1) * 14336 + w * 3584;
      char* lv = smem + 32768 + (p ^ 1) * 14336 + w * 3584;
      glds16(gv + lane * 16, lv);
      glds16(gv + 1024 + lane * 16, lv + 1024);
      glds16(gv + 2048 + lane * 16, lv + 2048);
      glds4(gv + 3072 + lane * 4, lv + 3072);
      glds4(gv + 3328 + lane * 4, lv + 3328);
    }

    // ---- QK^T for this wave's tile: S^T = K.X^T, C init = -|k|^2*lg2e/T ----
    const int kt = 2 * it + t;
    floatx16 acc;
    {
      const floatx4* kq = (const floatx4*)(ksqp + ((size_t)kt * 2 + hh) * 16);
#pragma unroll
      for (int j = 0; j < 4; ++j) {
        floatx4 v = kq[j];
        acc[4 * j + 0] = v[0]; acc[4 * j + 1] = v[1];
        acc[4 * j + 2] = v[2]; acc[4 * j + 3] = v[3];
      }
    }
#pragma unroll
    for (int dc = 0; dc < 8; ++dc) {
      short8 kf = *(const short8*)(Kb + (t * 8 + dc) * 1024 + lane * 16);
      acc = __builtin_amdgcn_mfma_f32_32x32x16_bf16(kf, xf[dc], acc, 0, 0, 0);
    }

    // ---- exp2 + pack + in-register transpose (permlane32_swap) ----
    unsigned int pr[8];
#pragma unroll
    for (int j = 0; j < 8; ++j)
      pr[j] = pk2bf(__builtin_amdgcn_exp2f(acc[2 * j]),
                    __builtin_amdgcn_exp2f(acc[2 * j + 1]));
    asm("v_permlane32_swap_b32 %0, %1" : "+v"(pr[0]), "+v"(pr[2]));
    asm("v_permlane32_swap_b32 %0, %1" : "+v"(pr[1]), "+v"(pr[3]));
    asm("v_permlane32_swap_b32 %0, %1" : "+v"(pr[4]), "+v"(pr[6]));
    asm("v_permlane32_swap_b32 %0, %1" : "+v"(pr[5]), "+v"(pr[7]));
    short8 paf[2];
    {
      union { short8 v; unsigned int ui[4]; } c0, c1;
      c0.ui[0] = pr[0]; c0.ui[1] = pr[1]; c0.ui[2] = pr[2]; c0.ui[3] = pr[3];
      c1.ui[0] = pr[4]; c1.ui[1] = pr[5]; c1.ui[2] = pr[6]; c1.ui[3] = pr[7];
      paf[0] = c0.v; paf[1] = c1.v;
    }

    // ---- PV: O += P.V (4 indep oacc chains; lane-linear b128 reads) ----
#pragma unroll
    for (int kc = 0; kc < 2; ++kc) {
      const char* unit = Vb + t * 7168 + kc * 3584;
#pragma unroll
      for (int nt = 0; nt < 3; ++nt) {
        short8 vf = *(const short8*)(unit + nt * 1024 + lane * 16);
        oacc[nt] = __builtin_amdgcn_mfma_f32_32x32x16_bf16(paf[kc], vf, oacc[nt], 0, 0, 0);
      }
      // nt=3 half-tile: cols 96..111 stored; 112..127 are zero
      short8 vf = *(const short8*)(unit + 3072 + (hh * 16 + (l31 & 15)) * 16);
      if (l31 >= 16) vf = (short8)0;
      oacc[3] = __builtin_amdgcn_mfma_f32_32x32x16_bf16(paf[kc], vf, oacc[3], 0, 0, 0);
    }
    __syncthreads();   // V/K(it) reads done + (it+1) staging landed
  }

  // ---- epilogue: combine key-tile partials (t=0/1) in LDS, normalize ----
  float* OL = (float*)smem;            // [64][105] fp32 = 26880 B, overlays bufs
  const int OLS = 105;
  float* rden = (float*)(smem + 26880);   // 64 floats
  if (t == 0) {
#pragma unroll
    for (int nt = 0; nt < 4; ++nt) {
      int col = nt * 32 + l31;
      if (col <= C_COLS) {
#pragma unroll
        for (int r = 0; r < 16; ++r) {
          int row = s * 32 + (r & 3) + 8 * (r >> 2) + 4 * hh;
          OL[row * OLS + col] = oacc[nt][r];
        }
      }
    }
  }
  __syncthreads();
  if (t == 1) {
#pragma unroll
    for (int nt = 0; nt < 4; ++nt) {
      int col = nt * 32 + l31;
      if (col <= C_COLS) {
#pragma unroll
        for (int r = 0; r < 16; ++r) {
          int row = s * 32 + (r & 3) + 8 * (r >> 2) + 4 * hh;
          OL[row * OLS + col] += oacc[nt][r];
        }
      }
    }
  }
  __syncthreads();
  if (tid < 64) rden[tid] = 1.0f / OL[tid * OLS + C_COLS];
  __syncthreads();
  float* outb = out + (size_t)rb * (64 * C_COLS);
  for (int idx = tid; idx < 64 * C_COLS; idx += 256) {
    int r = idx / C_COLS;
    int c = idx - r * C_COLS;
    outb[idx] = OL[r * OLS + c] * rden[r];
  }
}

extern "C" void kernel_launch(void* const* d_in, const int* in_sizes, int n_in,
                              void* d_out, int out_size, void* d_ws, size_t ws_size,
                              hipStream_t stream) {
  (void)in_sizes; (void)n_in; (void)out_size; (void)ws_size;
  const float* x      = (const float*)d_in[0];
  const float* keys   = (const float*)d_in[1];
  const float* values = (const float*)d_in[2];
  const float* temp   = (const float*)d_in[3];
  float* out = (float*)d_out;

  char* ws = (char*)d_ws;
  unsigned short* kp   = (unsigned short*)(ws);
  unsigned short* vp   = (unsigned short*)(ws + KP_BYTES);
  float*          ksqp = (float*)(ws + KSQ_OFF);

  hipLaunchKernelGGL(pack_k32,   dim3(256), dim3(256), 0, stream, keys, temp, kp, ksqp);
  hipLaunchKernelGGL(pack_v32,   dim3(256), dim3(256), 0, stream, values, vp);
  hipLaunchKernelGGL(attn_rbf32, dim3(512), dim3(256), 0, stream, x, kp, vp, ksqp, out);
}